// Round 18
// baseline (416.682 us; speedup 1.0000x reference)
//
#include <hip/hip_runtime.h>
#include <hip/hip_bf16.h>

#define N_NODES 100000
#define NPAD    100096
#define N_EDGES 600000
#define SCAN_B  98

typedef unsigned short u16;
typedef unsigned char u8;
typedef unsigned int u32;
typedef short bf16x8 __attribute__((ext_vector_type(8)));
typedef float f32x4 __attribute__((ext_vector_type(4)));
typedef float f32x2 __attribute__((ext_vector_type(2)));

__device__ __forceinline__ float4 ld4(const float* p){ return *(const float4*)p; }
__device__ __forceinline__ float sigm(float v){ return 1.0f/(1.0f + __expf(-v)); }
__device__ __forceinline__ float tanh_fast(float v){
  float e = __expf(-2.0f*fabsf(v));
  float r = (1.0f - e)/(1.0f + e);
  return copysignf(r, v);
}
// f32 -> bf16 bits, RNE
__device__ __forceinline__ u32 bfr(float f){
  u32 u = __float_as_uint(f);
  return (u + 0x7FFFu + ((u>>16)&1u)) >> 16;
}
__device__ __forceinline__ float b2f(u16 b){ return __uint_as_float(((u32)b)<<16); }
__device__ __forceinline__ uint4 pack8(float4 a, float4 b){
  uint4 r;
  r.x = bfr(a.x) | (bfr(a.y)<<16);
  r.y = bfr(a.z) | (bfr(a.w)<<16);
  r.z = bfr(b.x) | (bfr(b.y)<<16);
  r.w = bfr(b.z) | (bfr(b.w)<<16);
  return r;
}
__device__ __forceinline__ void gload16(const void* g, void* l){
  __builtin_amdgcn_global_load_lds((__attribute__((address_space(1))) void*)(g),
                                   (__attribute__((address_space(3))) void*)(l), 16, 0, 0);
}

// ==================== fused prep: cast2 + count + all weight packs ====================
#define PB_CAST   12512
#define PB_COUNT  2344
#define P0 (PB_CAST)
#define P1 (P0 + PB_COUNT)     // pack_gru (64)
#define P2 (P1 + 64)           // pack_sage l0 (16)
#define P3 (P2 + 16)           // l1
#define P4 (P3 + 16)           // l2
#define P5 (P4 + 16)           // pack_p (32)
#define P6 (P5 + 32)           // pack_e (4)
#define PREP_BLOCKS (P6 + 4)

__global__ __launch_bounds__(256) void k_prep(
    const float* __restrict__ x, const float* __restrict__ h0,
    u16* __restrict__ xb, u16* __restrict__ h0b,
    const int* __restrict__ ei, int* __restrict__ counts,
    const float* __restrict__ Wih, const float* __restrict__ Whh, u16* __restrict__ Wg,
    const float* __restrict__ Wl0, const float* __restrict__ Wr0, u16* __restrict__ Wgs0,
    const float* __restrict__ Wl1, const float* __restrict__ Wr1, u16* __restrict__ Wgs1,
    const float* __restrict__ Wl2, const float* __restrict__ Wr2, u16* __restrict__ Wgs2,
    const float* __restrict__ Wc1, u16* __restrict__ Wgp, u16* __restrict__ Wge)
{
  const int b = blockIdx.x, t = threadIdx.x;
  if (b < P0){
    int idx = b*256 + t;
    const int half = NPAD*16;
    const float* src = (idx < half) ? x : h0;
    u16* dst = (idx < half) ? xb : h0b;
    if (idx >= half) idx -= half;
    int row = idx >> 4, c8 = (idx & 15) << 3;
    float4 v0 = {0,0,0,0}, v1 = {0,0,0,0};
    if (row < N_NODES){
      v0 = ld4(src + (size_t)row*128 + c8);
      v1 = ld4(src + (size_t)row*128 + c8 + 4);
    }
    *(uint4*)(dst + (size_t)row*128 + c8) = pack8(v0, v1);
  } else if (b < P1){
    int e = (b - P0)*256 + t;
    if (e < N_EDGES) atomicAdd(&counts[ei[N_EDGES + e]], 1);
  } else if (b < P2){
    int cI = (b - P1)*256 + t;        // 16384
    int lane = cI&63, grp = (cI>>6)&7, ks = (cI>>9)&7, nb = cI>>12;
    int g = grp & 3;
    int c = (nb*2 + (grp>>2))*16 + (lane&15);
    int kg = ks*32 + ((lane>>4)<<3);
    bool xs = kg < 128;
    const float* src = nullptr;
    if (g == 0)      src = xs ? Wih + (size_t)c*128 + kg       : Whh + (size_t)c*128 + kg-128;
    else if (g == 1) src = xs ? Wih + (size_t)(128+c)*128 + kg : Whh + (size_t)(128+c)*128 + kg-128;
    else if (g == 2) src = xs ? Wih + (size_t)(256+c)*128 + kg : nullptr;
    else             src = xs ? nullptr                        : Whh + (size_t)(256+c)*128 + kg-128;
    float4 v0 = {0,0,0,0}, v1 = {0,0,0,0};
    if (src){ v0 = ld4(src); v1 = ld4(src+4); }
    ((uint4*)Wg)[cI] = pack8(v0, v1);
  } else if (b < P5){
    const float *Wl, *Wr; u16* Wo; int c;
    if (b < P3){ Wl = Wl0; Wr = Wr0; Wo = Wgs0; c = (b - P2)*256 + t; }
    else if (b < P4){ Wl = Wl1; Wr = Wr1; Wo = Wgs1; c = (b - P3)*256 + t; }
    else { Wl = Wl2; Wr = Wr2; Wo = Wgs2; c = (b - P4)*256 + t; }
    int lane = c&63, grp = (c>>6)&7, ks = c>>9;
    int col = grp*16 + (lane&15);
    int kg = ks*32 + ((lane>>4)<<3);
    const float* src = (kg < 128) ? Wl + (size_t)col*128 + kg : Wr + (size_t)col*128 + kg-128;
    ((uint4*)Wo)[c] = pack8(ld4(src), ld4(src+4));
  } else if (b < P6){
    // P pack: fp8-byte-layout permutation (half, B=pby1*2+nw, jj, cl)
    int c = (b - P5)*256 + t;         // 8192
    int lane = c&63, grp = (c>>6)&7, ks = (c>>9)&3, nb = c>>11;
    int cp = nb*128 + grp*16 + (lane&15);
    int kg = ks*32 + ((lane>>4)<<3);
    int half = cp >> 8;
    int pby1 = (cp >> 7) & 1, nw = (cp >> 6) & 1, jj = (cp >> 4) & 3, cl = cp & 15;
    int f = (pby1*2 + nw)*64 + jj*16 + cl;
    const float* src = Wc1 + (size_t)f*288 + half*128 + kg;
    ((uint4*)Wgp)[c] = pack8(ld4(src), ld4(src+4));
  } else {
    int c = (b - P6)*256 + t;         // 1024
    int lc = c & 63;
    int j = ((c>>6)<<4) + (lc & 15), k0 = (lc >> 4) << 3;
    const float* src = Wc1 + (size_t)j*288 + 256 + k0;
    ((uint4*)Wge)[c] = pack8(ld4(src), ld4(src+4));
  }
}

// ==================== GRU: 1024-thread block, full stripe, A staged once ====================
// 16 waves = 2 row (mw) x 8 col (wv); wave wv owns packed cols wv*64..+63.
__global__ __launch_bounds__(1024) void k_gru(
    const u16* __restrict__ xb, const u16* __restrict__ h0b,
    const u16* __restrict__ Wp, u16* __restrict__ outB,
    const float* __restrict__ bih, const float* __restrict__ bhh)
{
  __shared__ __align__(16) u16 As[4*512*8];    // 32KB
  const int t = threadIdx.x, L = t & 63, w = t >> 6;   // w 0..15
  const int mw = w >> 3, wv = w & 7;
  const int by = wv >> 1, nh = wv & 1;
  const int i0 = blockIdx.x * 128;
  const f32x4 z4 = {0.f,0.f,0.f,0.f};
  f32x4 acc[4][4];
#pragma unroll
  for (int i=0;i<4;++i)
#pragma unroll
  for (int j=0;j<4;++j) acc[i][j] = z4;

#pragma unroll
  for (int half = 0; half < 2; ++half){
    if (half) __syncthreads();
    const u16* Asrc = half ? h0b : xb;
#pragma unroll
    for (int sh = 0; sh < 4; ++sh){
      int s = t + sh*1024;                     // 4096 chunks
      int ks = s >> 9, rem = s & 511;
      int rg = rem >> 6, l2 = rem & 63;
      int row = i0 + rg*16 + (l2 & 15);
      int kg = ks*32 + ((l2 >> 4) << 3);
      gload16(Asrc + (size_t)row*128 + kg, As + (size_t)s*8);
    }
    __syncthreads();
#pragma unroll
    for (int ks = 0; ks < 4; ++ks){
      bf16x8 a[4], b[4];
#pragma unroll
      for (int j = 0; j < 4; ++j)
        b[j] = *(const bf16x8*)(Wp + (((size_t)(by*8 + half*4 + ks)) << 12) + ((nh*4+j)*64 + L)*8);
#pragma unroll
      for (int i = 0; i < 4; ++i)
        a[i] = *(const bf16x8*)(As + ((size_t)ks*512 + (mw*4+i)*64 + L)*8);
#pragma unroll
      for (int i = 0; i < 4; ++i)
#pragma unroll
        for (int j = 0; j < 4; ++j)
          acc[i][j] = __builtin_amdgcn_mfma_f32_16x16x32_bf16(a[i], b[j], acc[i][j], 0, 0, 0);
    }
  }
  const int r4 = (L>>4)*4, cL = L&15;
  // As holds h0b (bf16) for all 128 cols of this stripe
  const int c = wv*16 + cL;
  const float br = bih[c]     + bhh[c];
  const float bz = bih[128+c] + bhh[128+c];
  const float bi = bih[256+c];
  const float bh = bhh[256+c];
  const int ksp = c >> 5, hi = (c >> 3) & 3, jj = c & 7;
#pragma unroll
  for (int i = 0; i < 4; ++i){
    int rbase = i0 + mw*64 + i*16 + r4;
    const u16* hrow = As + ((size_t)ksp*512 + (mw*4+i)*64 + hi*16 + r4)*8 + jj;
#pragma unroll
    for (int q = 0; q < 4; ++q){
      int row = rbase + q;
      float rr = sigm(acc[i][0][q] + br);
      float zz = sigm(acc[i][1][q] + bz);
      float nn = tanh_fast(acc[i][2][q] + bi + rr*(acc[i][3][q] + bh));
      float h0v = b2f(hrow[q*8]);
      outB[(size_t)row*128 + c] = (u16)bfr((1.f - zz)*nn + zz*h0v);
    }
  }
}

// ==================== 2-phase A-stationary GEMM (sage): 32KB LDS, B streamed ====
__global__ __launch_bounds__(256) void k_mm3(
    const u16* __restrict__ A1, const u16* __restrict__ A2,
    const u16* __restrict__ Wp, const float* __restrict__ bias,
    u16* __restrict__ outB)
{
  __shared__ __align__(16) u16 As[4*512*8];    // 32KB
  const int t = threadIdx.x, L = t & 63, w = t >> 6;
  const int mw = w >> 1, nw = w & 1;
  const int i0 = blockIdx.y * 128;
  const f32x4 z4 = {0.f,0.f,0.f,0.f};
  f32x4 acc[4][4];
#pragma unroll
  for (int i=0;i<4;++i)
#pragma unroll
  for (int j=0;j<4;++j) acc[i][j] = z4;

#pragma unroll
  for (int half = 0; half < 2; ++half){
    if (half) __syncthreads();
    const u16* Asrc = half ? A2 : A1;
#pragma unroll
    for (int sh = 0; sh < 8; ++sh){
      int s = t + sh*256;
      int ks = s >> 9, rem = s & 511;
      int rg = rem >> 6, l2 = rem & 63;
      int row = i0 + rg*16 + (l2 & 15);
      int kg = ks*32 + ((l2 >> 4) << 3);
      gload16(Asrc + (size_t)row*128 + kg, As + (size_t)s*8);
    }
    __syncthreads();
#pragma unroll
    for (int ks = 0; ks < 4; ++ks){
      bf16x8 a[4], b[4];
#pragma unroll
      for (int j = 0; j < 4; ++j)
        b[j] = *(const bf16x8*)(Wp + (((size_t)(half*4 + ks)) << 12) + ((nw*4+j)*64 + L)*8);
#pragma unroll
      for (int i = 0; i < 4; ++i)
        a[i] = *(const bf16x8*)(As + ((size_t)ks*512 + (mw*4+i)*64 + L)*8);
#pragma unroll
      for (int i = 0; i < 4; ++i)
#pragma unroll
        for (int j = 0; j < 4; ++j)
          acc[i][j] = __builtin_amdgcn_mfma_f32_16x16x32_bf16(a[i], b[j], acc[i][j], 0, 0, 0);
    }
  }
  const int r4 = (L>>4)*4, cL = L&15;
#pragma unroll
  for (int i = 0; i < 4; ++i){
    int rbase = i0 + mw*64 + i*16 + r4;
#pragma unroll
    for (int j = 0; j < 4; ++j){
      int col = nw*64 + j*16 + cL;
#pragma unroll
      for (int q = 0; q < 4; ++q){
        int row = rbase + q;
        float rv = fmaxf(acc[i][j][q] + bias[col], 0.f);
        outB[(size_t)row*128 + col] = (u16)bfr(rv);
      }
    }
  }
}

// ==================== SAGE3 + P fused; P stored fp8 (x16 scale) ====================
#define H3P 136
__global__ __launch_bounds__(256) void k_sage3p(
    const u16* __restrict__ A1, const u16* __restrict__ A2,
    const u16* __restrict__ Ws, const float* __restrict__ bias,
    const u16* __restrict__ Wp,
    float* __restrict__ hfinF, u8* __restrict__ GP8)
{
  __shared__ __align__(16) u16 As[8*512*8];    // 64KB; reused as h3 [128][H3P]
  const int t = threadIdx.x, L = t & 63, w = t >> 6;
  const int mw = w >> 1, nw = w & 1;
  const int i0 = blockIdx.x * 128;
  const int r4 = (L>>4)*4, cL = L&15;
  const f32x4 z4 = {0.f,0.f,0.f,0.f};
#pragma unroll
  for (int sh = 0; sh < 16; ++sh){
    int s = t + sh*256;
    int ks = s >> 9, rem = s & 511;
    int rg = rem >> 6, l2 = rem & 63;
    int row = i0 + rg*16 + (l2 & 15);
    int kg = ks*32 + ((l2 >> 4) << 3);
    const u16* src = (ks < 4) ? A1 + (size_t)row*128 + kg
                              : A2 + (size_t)row*128 + kg - 128;
    gload16(src, As + (size_t)s*8);
  }
  __syncthreads();
  f32x4 acc[4][4];
#pragma unroll
  for (int i=0;i<4;++i)
#pragma unroll
  for (int j=0;j<4;++j) acc[i][j] = z4;
#pragma unroll
  for (int ks = 0; ks < 8; ++ks){
    bf16x8 a[4], b[4];
#pragma unroll
    for (int j = 0; j < 4; ++j)
      b[j] = *(const bf16x8*)(Ws + (((size_t)ks) << 12) + ((nw*4+j)*64 + L)*8);
#pragma unroll
    for (int i = 0; i < 4; ++i)
      a[i] = *(const bf16x8*)(As + ((size_t)ks*512 + (mw*4+i)*64 + L)*8);
#pragma unroll
    for (int i = 0; i < 4; ++i)
#pragma unroll
      for (int j = 0; j < 4; ++j)
        acc[i][j] = __builtin_amdgcn_mfma_f32_16x16x32_bf16(a[i], b[j], acc[i][j], 0, 0, 0);
  }
  __syncthreads();
  u16* h3l = As;
#pragma unroll
  for (int i = 0; i < 4; ++i){
    int rl = mw*64 + i*16 + r4;
#pragma unroll
    for (int j = 0; j < 4; ++j){
      int col = nw*64 + j*16 + cL;
#pragma unroll
      for (int q = 0; q < 4; ++q){
        float rv = fmaxf(acc[i][j][q] + bias[col], 0.f);
        h3l[(rl + q)*H3P + col] = (u16)bfr(rv);
        int row = i0 + rl + q;
        if (row < N_NODES) hfinF[(size_t)row*128 + col] = rv;
      }
    }
  }
  __syncthreads();
  for (int pby = 0; pby < 4; ++pby){
#pragma unroll
    for (int i=0;i<4;++i)
#pragma unroll
    for (int j=0;j<4;++j) acc[i][j] = z4;
#pragma unroll
    for (int ks = 0; ks < 4; ++ks){
      bf16x8 a[4], b[4];
#pragma unroll
      for (int j = 0; j < 4; ++j)
        b[j] = *(const bf16x8*)(Wp + (((size_t)(pby*4 + ks)) << 12) + ((nw*4+j)*64 + L)*8);
      int kg = ks*32 + ((L>>4)<<3);
#pragma unroll
      for (int i = 0; i < 4; ++i){
        int rl = mw*64 + i*16 + cL;
        a[i] = *(const bf16x8*)(h3l + rl*H3P + kg);
      }
#pragma unroll
      for (int i = 0; i < 4; ++i)
#pragma unroll
        for (int j = 0; j < 4; ++j)
          acc[i][j] = __builtin_amdgcn_mfma_f32_16x16x32_bf16(a[i], b[j], acc[i][j], 0, 0, 0);
    }
    // fp8 epilogue: j-quad -> one u32; byte addr = half*256 + B*64 + cL*4 + j
    const int halfp = pby >> 1, Bb = (pby & 1)*2 + nw;
#pragma unroll
    for (int i = 0; i < 4; ++i){
      int rbase = i0 + mw*64 + i*16 + r4;
#pragma unroll
      for (int q = 0; q < 4; ++q){
        u32 pk = (u32)__builtin_amdgcn_cvt_pk_fp8_f32(acc[i][0][q]*16.f, acc[i][1][q]*16.f, 0, false);
        pk = (u32)__builtin_amdgcn_cvt_pk_fp8_f32(acc[i][2][q]*16.f, acc[i][3][q]*16.f, (int)pk, true);
        *(u32*)(GP8 + (size_t)(rbase + q)*512 + halfp*256 + Bb*64 + cL*4) = pk;
      }
    }
  }
}

// ==================== CSR build ====================
__global__ __launch_bounds__(1024) void k_scan1(const int* __restrict__ counts,
    int* __restrict__ offs, int* __restrict__ bsum)
{
  __shared__ int wsum[16];
  const int t = threadIdx.x, lane = t & 63, w = t >> 6;
  int i = blockIdx.x*1024 + t;
  int v = (i < N_NODES) ? counts[i] : 0;
  int s = v;
#pragma unroll
  for (int d = 1; d < 64; d <<= 1){ int u = __shfl_up(s, d, 64); if (lane >= d) s += u; }
  if (lane == 63) wsum[w] = s;
  __syncthreads();
  if (w == 0){
    int ws = (lane < 16) ? wsum[lane] : 0;
#pragma unroll
    for (int d = 1; d < 16; d <<= 1){ int u = __shfl_up(ws, d, 64); if (lane >= d) ws += u; }
    if (lane < 16) wsum[lane] = ws;
  }
  __syncthreads();
  int wbase = (w == 0) ? 0 : wsum[w-1];
  if (i < N_NODES) offs[i] = wbase + s - v;
  if (t == 0) bsum[blockIdx.x] = wsum[15];
}

__global__ void k_scan2(int* __restrict__ bsum, int* __restrict__ offs){
  __shared__ int wtot;
  const int t = threadIdx.x, lane = t & 63, w = t >> 6;  // 128 threads
  int v = (t < SCAN_B) ? bsum[t] : 0;
  int s = v;
#pragma unroll
  for (int d = 1; d < 64; d <<= 1){ int u = __shfl_up(s, d, 64); if (lane >= d) s += u; }
  if (t == 63) wtot = s;
  __syncthreads();
  int base = (w == 1) ? wtot : 0;
  int excl = base + s - v;
  if (t < SCAN_B) bsum[t] = excl;
  if (t == SCAN_B-1) offs[N_NODES] = excl + v;
}

__global__ __launch_bounds__(1024) void k_scan3(const int* __restrict__ bsum,
    int* __restrict__ offs, int* __restrict__ cursor)
{
  int i = blockIdx.x*1024 + threadIdx.x;
  if (i < N_NODES){
    int o = offs[i] + bsum[blockIdx.x];
    offs[i] = o; cursor[i] = o;
  }
}

__global__ void k_fill(const int* __restrict__ ei, int* __restrict__ cursor,
                       int* __restrict__ lstS, int* __restrict__ lstD, int* __restrict__ lstE){
  int e = blockIdx.x*256 + threadIdx.x;
  if (e < N_EDGES){
    int s = ei[e], d = ei[N_EDGES + e];
    int slot = atomicAdd(&cursor[d], 1);
    lstS[slot] = s; lstD[slot] = d; lstE[slot] = e;
  }
}

// ==================== mean aggregation (bf16): 16 lanes/node, uint4, 4-deep ====================
#define AGG_ACC(v) \
  a0 += __uint_as_float((v).x<<16); a1 += __uint_as_float((v).x & 0xFFFF0000u); \
  a2 += __uint_as_float((v).y<<16); a3 += __uint_as_float((v).y & 0xFFFF0000u); \
  a4 += __uint_as_float((v).z<<16); a5 += __uint_as_float((v).z & 0xFFFF0000u); \
  a6 += __uint_as_float((v).w<<16); a7 += __uint_as_float((v).w & 0xFFFF0000u);

__global__ __launch_bounds__(256) void k_agg(const u16* __restrict__ hb,
    const int* __restrict__ offs, const int* __restrict__ lst, u16* __restrict__ meanb)
{
  const int node = blockIdx.x*16 + (threadIdx.x >> 4);
  if (node >= NPAD) return;
  const int l16 = threadIdx.x & 15;
  int beg = 0, end = 0;
  if (node < N_NODES){ beg = offs[node]; end = offs[node+1]; }
  float a0=0.f,a1=0.f,a2=0.f,a3=0.f,a4=0.f,a5=0.f,a6=0.f,a7=0.f;
  int p = beg;
  for (; p + 4 <= end; p += 4){
    int s0 = lst[p], s1 = lst[p+1], s2 = lst[p+2], s3 = lst[p+3];
    uint4 v0 = *(const uint4*)(hb + (size_t)s0*128 + l16*8);
    uint4 v1 = *(const uint4*)(hb + (size_t)s1*128 + l16*8);
    uint4 v2 = *(const uint4*)(hb + (size_t)s2*128 + l16*8);
    uint4 v3 = *(const uint4*)(hb + (size_t)s3*128 + l16*8);
    AGG_ACC(v0) AGG_ACC(v1) AGG_ACC(v2) AGG_ACC(v3)
  }
  for (; p < end; ++p){
    uint4 v0 = *(const uint4*)(hb + (size_t)lst[p]*128 + l16*8);
    AGG_ACC(v0)
  }
  float inv = 1.f / fmaxf((float)(end - beg), 1.f);
  uint4 o;
  o.x = bfr(a0*inv) | (bfr(a1*inv)<<16);
  o.y = bfr(a2*inv) | (bfr(a3*inv)<<16);
  o.z = bfr(a4*inv) | (bfr(a5*inv)<<16);
  o.w = bfr(a6*inv) | (bfr(a7*inv)<<16);
  *(uint4*)(meanb + (size_t)node*128 + l16*8) = o;
}

// ==================== per-edge classifier: fp8 P gathers (4x uint4/side), pinned ====
__global__ __launch_bounds__(256) void k_edge(
    const int* __restrict__ lstS, const int* __restrict__ lstD, const int* __restrict__ lstE,
    const float* __restrict__ ea, const u8* __restrict__ P8, const u16* __restrict__ Wg_e,
    const float* __restrict__ bc1, const float* __restrict__ Wc2, const float* __restrict__ bc2,
    float* __restrict__ outp)
{
  __shared__ __align__(16) u16 Bf[16*64*8];    // 16KB: A3 as MFMA A-frags (prepacked)
  __shared__ float sb[256], sw[256];
  const int t = threadIdx.x, L = t & 63, w = t >> 6;
#pragma unroll
  for (int i = 0; i < 4; ++i){
    int c = t + i*256;
    gload16(Wg_e + c*8, Bf + c*8);
  }
  sb[t] = bc1[t];
  sw[t] = Wc2[t];
  const int cL = L & 15, part = L >> 4;
  const float bc2v = bc2[0];
  const int pos0 = blockIdx.x*64 + w*16;
  const int e = lstE[pos0 + cL];
  const int s = lstS[pos0 + cL], d = lstD[pos0 + cL];
  bf16x8 eafrag;
  {
    const float* src = ea + (size_t)e*32 + part*8;
    uint4 pk = pack8(ld4(src), ld4(src+4));
    eafrag = *(bf16x8*)&pk;
  }
  const u8* p1base = P8 + (size_t)s*512 + part*16;
  const u8* p2base = P8 + (size_t)d*512 + 256 + part*16;
  uint4 g1[4], g2[4];
#pragma unroll
  for (int B = 0; B < 4; ++B){
    g1[B] = *(const uint4*)(p1base + B*64);
    g2[B] = *(const uint4*)(p2base + B*64);
  }
  // pin all 8 gathers in flight
  __builtin_amdgcn_sched_barrier(0);
#pragma unroll
  for (int B = 0; B < 4; ++B){
    asm volatile("" :: "v"(g1[B].x), "v"(g1[B].y), "v"(g1[B].z), "v"(g1[B].w),
                       "v"(g2[B].x), "v"(g2[B].y), "v"(g2[B].z), "v"(g2[B].w));
  }
  __syncthreads();
  float osum = 0.f;
#pragma unroll
  for (int B = 0; B < 4; ++B){
    const u32 w1[4] = {g1[B].x, g1[B].y, g1[B].z, g1[B].w};
    const u32 w2[4] = {g2[B].x, g2[B].y, g2[B].z, g2[B].w};
    float p1v[4][4], p2v[4][4];   // [q][jbl]
#pragma unroll
    for (int q = 0; q < 4; ++q){
      f32x2 l1 = __builtin_amdgcn_cvt_pk_f32_fp8((int)w1[q], false);
      f32x2 h1 = __builtin_amdgcn_cvt_pk_f32_fp8((int)w1[q], true);
      f32x2 l2 = __builtin_amdgcn_cvt_pk_f32_fp8((int)w2[q], false);
      f32x2 h2 = __builtin_amdgcn_cvt_pk_f32_fp8((int)w2[q], true);
      p1v[q][0] = l1.x; p1v[q][1] = l1.y; p1v[q][2] = h1.x; p1v[q][3] = h1.y;
      p2v[q][0] = l2.x; p2v[q][1] = l2.y; p2v[q][2] = h2.x; p2v[q][3] = h2.y;
    }
#pragma unroll
    for (int jbl = 0; jbl < 4; ++jbl){
      const int jb = 4*B + jbl;
      f32x4 acc = {0.f,0.f,0.f,0.f};
      bf16x8 afr = *(const bf16x8*)(Bf + ((jb*64 + L)<<3));
      acc = __builtin_amdgcn_mfma_f32_16x16x32_bf16(afr, eafrag, acc, 0, 0, 0);
      float4 bb = *(const float4*)&sb[jb*16 + part*4];
      float4 ww = *(const float4*)&sw[jb*16 + part*4];
      float bbv[4]={bb.x,bb.y,bb.z,bb.w}, wwv[4]={ww.x,ww.y,ww.z,ww.w};
#pragma unroll
      for (int q = 0; q < 4; ++q){
        float hid = fmaxf(acc[q] + (p1v[q][jbl] + p2v[q][jbl])*0.0625f + bbv[q], 0.f);
        osum = fmaf(wwv[q], hid, osum);
      }
    }
  }
  osum += __shfl_xor(osum, 16, 64);
  osum += __shfl_xor(osum, 32, 64);
  if (L < 16) outp[e] = osum + bc2v;
}

extern "C" void kernel_launch(void* const* d_in, const int* in_sizes, int n_in,
                              void* d_out, int out_size, void* d_ws, size_t ws_size,
                              hipStream_t stream)
{
  const float* x   = (const float*)d_in[0];
  const float* h0  = (const float*)d_in[1];
  const int*   ei  = (const int*)d_in[2];
  const float* ea  = (const float*)d_in[3];
  const float* Wih = (const float*)d_in[4];
  const float* Whh = (const float*)d_in[5];
  const float* bih = (const float*)d_in[6];
  const float* bhh = (const float*)d_in[7];
  const float* Wl[3] = {(const float*)d_in[8],  (const float*)d_in[11], (const float*)d_in[14]};
  const float* bl[3] = {(const float*)d_in[9],  (const float*)d_in[12], (const float*)d_in[15]};
  const float* Wr[3] = {(const float*)d_in[10], (const float*)d_in[13], (const float*)d_in[16]};
  const float* Wc1 = (const float*)d_in[17];
  const float* bc1 = (const float*)d_in[18];
  const float* Wc2 = (const float*)d_in[19];
  const float* bc2 = (const float*)d_in[20];

  float* out  = (float*)d_out;
  float* hfin = (float*)d_out + N_EDGES;

  char* wp = (char*)d_ws;
  auto alloc = [&](size_t bytes) -> void* {
    void* p = (void*)wp; wp += (bytes + 255) & ~(size_t)255; return p;
  };
  u16* xb   = (u16*)alloc((size_t)NPAD*128*2);
  u16* h0b  = (u16*)alloc((size_t)NPAD*128*2);
  u16* hA   = (u16*)alloc((size_t)NPAD*128*2);
  u16* hB   = (u16*)alloc((size_t)NPAD*128*2);
  u16* mb   = (u16*)alloc((size_t)NPAD*128*2);
  u8*  GP8  = (u8*) alloc((size_t)NPAD*512);
  u16* Wg_g = (u16*)alloc((size_t)16384*16);
  u16* Wg_s0= (u16*)alloc((size_t)4096*16);
  u16* Wg_s1= (u16*)alloc((size_t)4096*16);
  u16* Wg_s2= (u16*)alloc((size_t)4096*16);
  u16* Wg_p = (u16*)alloc((size_t)8192*16);
  u16* Wg_e = (u16*)alloc((size_t)1024*16);
  int* counts=(int*)alloc((size_t)N_NODES*4);
  int* cursor=(int*)alloc((size_t)N_NODES*4);
  int* offs  =(int*)alloc((size_t)(N_NODES+1)*4);
  int* bsum  =(int*)alloc((size_t)SCAN_B*4);
  int* lstS  =(int*)alloc((size_t)N_EDGES*4);
  int* lstD  =(int*)alloc((size_t)N_EDGES*4);
  int* lstE  =(int*)alloc((size_t)N_EDGES*4);

  const dim3 b256(256);

  // fused prep (cast + count + packs), then scan + fill
  (void)hipMemsetAsync(counts, 0, (size_t)N_NODES*4, stream);
  k_prep<<<dim3(PREP_BLOCKS), b256, 0, stream>>>(
      x, h0, xb, h0b, ei, counts,
      Wih, Whh, Wg_g,
      Wl[0], Wr[0], Wg_s0, Wl[1], Wr[1], Wg_s1, Wl[2], Wr[2], Wg_s2,
      Wc1, Wg_p, Wg_e);
  k_scan1<<<dim3(SCAN_B), dim3(1024), 0, stream>>>(counts, offs, bsum);
  k_scan2<<<dim3(1), dim3(128), 0, stream>>>(bsum, offs);
  k_scan3<<<dim3(SCAN_B), dim3(1024), 0, stream>>>(bsum, offs, cursor);
  k_fill<<<dim3((N_EDGES+255)/256), b256, 0, stream>>>(ei, cursor, lstS, lstD, lstE);

  // GRU: 1024-thread full-stripe GEMM + gates -> hA (bf16); A staged once
  k_gru<<<dim3(782), dim3(1024), 0, stream>>>(xb, h0b, Wg_g, hA, bih, bhh);

  // SAGE 1,2 (2-phase A-stationary); SAGE3 fused with P GEMM (fp8 P out)
  k_agg<<<dim3(6256), b256, 0, stream>>>(hA, offs, lstS, mb);
  k_mm3<<<dim3(1,782), b256, 0, stream>>>(mb, hA, Wg_s0, bl[0], hB);
  k_agg<<<dim3(6256), b256, 0, stream>>>(hB, offs, lstS, mb);
  k_mm3<<<dim3(1,782), b256, 0, stream>>>(mb, hB, Wg_s1, bl[1], hA);
  k_agg<<<dim3(6256), b256, 0, stream>>>(hA, offs, lstS, mb);
  k_sage3p<<<dim3(782), b256, 0, stream>>>(mb, hA, Wg_s2, bl[2], Wg_p, hfin, GP8);

  // per-edge classifier in CSR order
  k_edge<<<dim3(9375), b256, 0, stream>>>(lstS, lstD, lstE, ea, GP8, Wg_e, bc1, Wc2, bc2, out);
}

// Round 19
// 386.819 us; speedup vs baseline: 1.0772x; 1.0772x over previous
//
#include <hip/hip_runtime.h>
#include <hip/hip_bf16.h>

#define N_NODES 100000
#define NPAD    100096
#define N_EDGES 600000
#define SCAN_B  98

typedef unsigned short u16;
typedef unsigned char u8;
typedef unsigned int u32;
typedef short bf16x8 __attribute__((ext_vector_type(8)));
typedef float f32x4 __attribute__((ext_vector_type(4)));
typedef float f32x2 __attribute__((ext_vector_type(2)));

__device__ __forceinline__ float4 ld4(const float* p){ return *(const float4*)p; }
__device__ __forceinline__ float sigm(float v){ return 1.0f/(1.0f + __expf(-v)); }
__device__ __forceinline__ float tanh_fast(float v){
  float e = __expf(-2.0f*fabsf(v));
  float r = (1.0f - e)/(1.0f + e);
  return copysignf(r, v);
}
// f32 -> bf16 bits, RNE
__device__ __forceinline__ u32 bfr(float f){
  u32 u = __float_as_uint(f);
  return (u + 0x7FFFu + ((u>>16)&1u)) >> 16;
}
__device__ __forceinline__ float b2f(u16 b){ return __uint_as_float(((u32)b)<<16); }
__device__ __forceinline__ uint4 pack8(float4 a, float4 b){
  uint4 r;
  r.x = bfr(a.x) | (bfr(a.y)<<16);
  r.y = bfr(a.z) | (bfr(a.w)<<16);
  r.z = bfr(b.x) | (bfr(b.y)<<16);
  r.w = bfr(b.z) | (bfr(b.w)<<16);
  return r;
}
__device__ __forceinline__ void gload16(const void* g, void* l){
  __builtin_amdgcn_global_load_lds((__attribute__((address_space(1))) void*)(g),
                                   (__attribute__((address_space(3))) void*)(l), 16, 0, 0);
}

// ==================== fused prep: cast2 + count + all weight packs ====================
#define PB_CAST   12512
#define PB_COUNT  2344
#define P0 (PB_CAST)
#define P1 (P0 + PB_COUNT)     // pack_gru (64)
#define P2 (P1 + 64)           // pack_sage l0 (16)
#define P3 (P2 + 16)           // l1
#define P4 (P3 + 16)           // l2
#define P5 (P4 + 16)           // pack_p (32)
#define P6 (P5 + 32)           // pack_e (4)
#define PREP_BLOCKS (P6 + 4)

__global__ __launch_bounds__(256) void k_prep(
    const float* __restrict__ x, const float* __restrict__ h0,
    u16* __restrict__ xb, u16* __restrict__ h0b,
    const int* __restrict__ ei, int* __restrict__ counts,
    const float* __restrict__ Wih, const float* __restrict__ Whh, u16* __restrict__ Wg,
    const float* __restrict__ Wl0, const float* __restrict__ Wr0, u16* __restrict__ Wgs0,
    const float* __restrict__ Wl1, const float* __restrict__ Wr1, u16* __restrict__ Wgs1,
    const float* __restrict__ Wl2, const float* __restrict__ Wr2, u16* __restrict__ Wgs2,
    const float* __restrict__ Wc1, u16* __restrict__ Wgp, u16* __restrict__ Wge)
{
  const int b = blockIdx.x, t = threadIdx.x;
  if (b < P0){
    int idx = b*256 + t;
    const int half = NPAD*16;
    const float* src = (idx < half) ? x : h0;
    u16* dst = (idx < half) ? xb : h0b;
    if (idx >= half) idx -= half;
    int row = idx >> 4, c8 = (idx & 15) << 3;
    float4 v0 = {0,0,0,0}, v1 = {0,0,0,0};
    if (row < N_NODES){
      v0 = ld4(src + (size_t)row*128 + c8);
      v1 = ld4(src + (size_t)row*128 + c8 + 4);
    }
    *(uint4*)(dst + (size_t)row*128 + c8) = pack8(v0, v1);
  } else if (b < P1){
    int e = (b - P0)*256 + t;
    if (e < N_EDGES) atomicAdd(&counts[ei[N_EDGES + e]], 1);
  } else if (b < P2){
    int cI = (b - P1)*256 + t;        // 16384
    int lane = cI&63, grp = (cI>>6)&7, ks = (cI>>9)&7, nb = cI>>12;
    int g = grp & 3;
    int c = (nb*2 + (grp>>2))*16 + (lane&15);
    int kg = ks*32 + ((lane>>4)<<3);
    bool xs = kg < 128;
    const float* src = nullptr;
    if (g == 0)      src = xs ? Wih + (size_t)c*128 + kg       : Whh + (size_t)c*128 + kg-128;
    else if (g == 1) src = xs ? Wih + (size_t)(128+c)*128 + kg : Whh + (size_t)(128+c)*128 + kg-128;
    else if (g == 2) src = xs ? Wih + (size_t)(256+c)*128 + kg : nullptr;
    else             src = xs ? nullptr                        : Whh + (size_t)(256+c)*128 + kg-128;
    float4 v0 = {0,0,0,0}, v1 = {0,0,0,0};
    if (src){ v0 = ld4(src); v1 = ld4(src+4); }
    ((uint4*)Wg)[cI] = pack8(v0, v1);
  } else if (b < P5){
    const float *Wl, *Wr; u16* Wo; int c;
    if (b < P3){ Wl = Wl0; Wr = Wr0; Wo = Wgs0; c = (b - P2)*256 + t; }
    else if (b < P4){ Wl = Wl1; Wr = Wr1; Wo = Wgs1; c = (b - P3)*256 + t; }
    else { Wl = Wl2; Wr = Wr2; Wo = Wgs2; c = (b - P4)*256 + t; }
    int lane = c&63, grp = (c>>6)&7, ks = c>>9;
    int col = grp*16 + (lane&15);
    int kg = ks*32 + ((lane>>4)<<3);
    const float* src = (kg < 128) ? Wl + (size_t)col*128 + kg : Wr + (size_t)col*128 + kg-128;
    ((uint4*)Wo)[c] = pack8(ld4(src), ld4(src+4));
  } else if (b < P6){
    // P pack: fp8-byte-layout permutation. Packed col cp -> true feature:
    // half=cp>>8, pby1=(cp>>7)&1, nw=(cp>>6)&1, jj=(cp>>4)&3, cl=cp&15;
    // B=pby1*2+nw, f = B*64 + jj*16 + cl (within half).
    int c = (b - P5)*256 + t;         // 8192
    int lane = c&63, grp = (c>>6)&7, ks = (c>>9)&3, nb = c>>11;
    int cp = nb*128 + grp*16 + (lane&15);
    int kg = ks*32 + ((lane>>4)<<3);
    int half = cp >> 8;
    int pby1 = (cp >> 7) & 1, nw = (cp >> 6) & 1, jj = (cp >> 4) & 3, cl = cp & 15;
    int f = (pby1*2 + nw)*64 + jj*16 + cl;
    const float* src = Wc1 + (size_t)f*288 + half*128 + kg;
    ((uint4*)Wgp)[c] = pack8(ld4(src), ld4(src+4));
  } else {
    int c = (b - P6)*256 + t;         // 1024
    int lc = c & 63;
    int j = ((c>>6)<<4) + (lc & 15), k0 = (lc >> 4) << 3;
    const float* src = Wc1 + (size_t)j*288 + 256 + k0;
    ((uint4*)Wge)[c] = pack8(ld4(src), ld4(src+4));
  }
}

// ==================== 2-phase A-stationary GEMM: 32KB LDS, B streamed global->reg ====
template<int EPI, int NOUT>
__global__ __launch_bounds__(256) void k_mm3(
    const u16* __restrict__ A1, const u16* __restrict__ A2,
    const u16* __restrict__ Wp, const float* __restrict__ bias,
    u16* __restrict__ outB,
    const float* __restrict__ bih, const float* __restrict__ bhh)
{
  __shared__ __align__(16) u16 As[4*512*8];    // 32KB
  const int t = threadIdx.x, L = t & 63, w = t >> 6;
  const int mw = w >> 1, nw = w & 1;
  const int i0 = blockIdx.y * 128, by = blockIdx.x;
  const f32x4 z4 = {0.f,0.f,0.f,0.f};
  f32x4 acc[4][4];
#pragma unroll
  for (int i=0;i<4;++i)
#pragma unroll
  for (int j=0;j<4;++j) acc[i][j] = z4;

#pragma unroll
  for (int half = 0; half < 2; ++half){
    if (half) __syncthreads();
    const u16* Asrc = half ? A2 : A1;
#pragma unroll
    for (int sh = 0; sh < 8; ++sh){
      int s = t + sh*256;
      int ks = s >> 9, rem = s & 511;
      int rg = rem >> 6, l2 = rem & 63;
      int row = i0 + rg*16 + (l2 & 15);
      int kg = ks*32 + ((l2 >> 4) << 3);
      gload16(Asrc + (size_t)row*128 + kg, As + (size_t)s*8);
    }
    __syncthreads();
#pragma unroll
    for (int ks = 0; ks < 4; ++ks){
      bf16x8 a[4], b[4];
#pragma unroll
      for (int j = 0; j < 4; ++j)
        b[j] = *(const bf16x8*)(Wp + (((size_t)(by*8 + half*4 + ks)) << 12) + ((nw*4+j)*64 + L)*8);
#pragma unroll
      for (int i = 0; i < 4; ++i)
        a[i] = *(const bf16x8*)(As + ((size_t)ks*512 + (mw*4+i)*64 + L)*8);
#pragma unroll
      for (int i = 0; i < 4; ++i)
#pragma unroll
        for (int j = 0; j < 4; ++j)
          acc[i][j] = __builtin_amdgcn_mfma_f32_16x16x32_bf16(a[i], b[j], acc[i][j], 0, 0, 0);
    }
  }
  const int r4 = (L>>4)*4, cL = L&15;
  if (EPI == 3){
    const int c = (by*2 + nw)*16 + cL;
    const float br = bih[c]     + bhh[c];
    const float bz = bih[128+c] + bhh[128+c];
    const float bi = bih[256+c];
    const float bh = bhh[256+c];
    const int ksp = c >> 5, hi = (c >> 3) & 3, jj = c & 7;
#pragma unroll
    for (int i = 0; i < 4; ++i){
      int rbase = i0 + mw*64 + i*16 + r4;
      const u16* hrow = As + ((size_t)ksp*512 + (mw*4+i)*64 + hi*16 + r4)*8 + jj;
#pragma unroll
      for (int q = 0; q < 4; ++q){
        int row = rbase + q;
        float rr = sigm(acc[i][0][q] + br);
        float zz = sigm(acc[i][1][q] + bz);
        float nn = tanh_fast(acc[i][2][q] + bi + rr*(acc[i][3][q] + bh));
        float h0v = b2f(hrow[q*8]);
        outB[(size_t)row*128 + c] = (u16)bfr((1.f - zz)*nn + zz*h0v);
      }
    }
  } else {
#pragma unroll
    for (int i = 0; i < 4; ++i){
      int rbase = i0 + mw*64 + i*16 + r4;
#pragma unroll
      for (int j = 0; j < 4; ++j){
        int col = by*128 + nw*64 + j*16 + cL;
#pragma unroll
        for (int q = 0; q < 4; ++q){
          int row = rbase + q;
          float rv = fmaxf(acc[i][j][q] + bias[col], 0.f);
          outB[(size_t)row*NOUT + col] = (u16)bfr(rv);
        }
      }
    }
  }
}

// ==================== SAGE3 + P fused; P stored fp8 (x16 scale) ====================
#define H3P 136
__global__ __launch_bounds__(256) void k_sage3p(
    const u16* __restrict__ A1, const u16* __restrict__ A2,
    const u16* __restrict__ Ws, const float* __restrict__ bias,
    const u16* __restrict__ Wp,
    float* __restrict__ hfinF, u8* __restrict__ GP8)
{
  __shared__ __align__(16) u16 As[8*512*8];    // 64KB; reused as h3 [128][H3P]
  const int t = threadIdx.x, L = t & 63, w = t >> 6;
  const int mw = w >> 1, nw = w & 1;
  const int i0 = blockIdx.x * 128;
  const int r4 = (L>>4)*4, cL = L&15;
  const f32x4 z4 = {0.f,0.f,0.f,0.f};
#pragma unroll
  for (int sh = 0; sh < 16; ++sh){
    int s = t + sh*256;
    int ks = s >> 9, rem = s & 511;
    int rg = rem >> 6, l2 = rem & 63;
    int row = i0 + rg*16 + (l2 & 15);
    int kg = ks*32 + ((l2 >> 4) << 3);
    const u16* src = (ks < 4) ? A1 + (size_t)row*128 + kg
                              : A2 + (size_t)row*128 + kg - 128;
    gload16(src, As + (size_t)s*8);
  }
  __syncthreads();
  f32x4 acc[4][4];
#pragma unroll
  for (int i=0;i<4;++i)
#pragma unroll
  for (int j=0;j<4;++j) acc[i][j] = z4;
#pragma unroll
  for (int ks = 0; ks < 8; ++ks){
    bf16x8 a[4], b[4];
#pragma unroll
    for (int j = 0; j < 4; ++j)
      b[j] = *(const bf16x8*)(Ws + (((size_t)ks) << 12) + ((nw*4+j)*64 + L)*8);
#pragma unroll
    for (int i = 0; i < 4; ++i)
      a[i] = *(const bf16x8*)(As + ((size_t)ks*512 + (mw*4+i)*64 + L)*8);
#pragma unroll
    for (int i = 0; i < 4; ++i)
#pragma unroll
      for (int j = 0; j < 4; ++j)
        acc[i][j] = __builtin_amdgcn_mfma_f32_16x16x32_bf16(a[i], b[j], acc[i][j], 0, 0, 0);
  }
  __syncthreads();
  u16* h3l = As;
#pragma unroll
  for (int i = 0; i < 4; ++i){
    int rl = mw*64 + i*16 + r4;
#pragma unroll
    for (int j = 0; j < 4; ++j){
      int col = nw*64 + j*16 + cL;
#pragma unroll
      for (int q = 0; q < 4; ++q){
        float rv = fmaxf(acc[i][j][q] + bias[col], 0.f);
        h3l[(rl + q)*H3P + col] = (u16)bfr(rv);
        int row = i0 + rl + q;
        if (row < N_NODES) hfinF[(size_t)row*128 + col] = rv;
      }
    }
  }
  __syncthreads();
  for (int pby = 0; pby < 4; ++pby){
#pragma unroll
    for (int i=0;i<4;++i)
#pragma unroll
    for (int j=0;j<4;++j) acc[i][j] = z4;
#pragma unroll
    for (int ks = 0; ks < 4; ++ks){
      bf16x8 a[4], b[4];
#pragma unroll
      for (int j = 0; j < 4; ++j)
        b[j] = *(const bf16x8*)(Wp + (((size_t)(pby*4 + ks)) << 12) + ((nw*4+j)*64 + L)*8);
      int kg = ks*32 + ((L>>4)<<3);
#pragma unroll
      for (int i = 0; i < 4; ++i){
        int rl = mw*64 + i*16 + cL;
        a[i] = *(const bf16x8*)(h3l + rl*H3P + kg);
      }
#pragma unroll
      for (int i = 0; i < 4; ++i)
#pragma unroll
        for (int j = 0; j < 4; ++j)
          acc[i][j] = __builtin_amdgcn_mfma_f32_16x16x32_bf16(a[i], b[j], acc[i][j], 0, 0, 0);
    }
    // fp8 epilogue: j-quad -> one u32; byte addr = half*256 + B*64 + cL*4 + j
    const int halfp = pby >> 1, Bb = (pby & 1)*2 + nw;
#pragma unroll
    for (int i = 0; i < 4; ++i){
      int rbase = i0 + mw*64 + i*16 + r4;
#pragma unroll
      for (int q = 0; q < 4; ++q){
        u32 pk = (u32)__builtin_amdgcn_cvt_pk_fp8_f32(acc[i][0][q]*16.f, acc[i][1][q]*16.f, 0, false);
        pk = (u32)__builtin_amdgcn_cvt_pk_fp8_f32(acc[i][2][q]*16.f, acc[i][3][q]*16.f, (int)pk, true);
        *(u32*)(GP8 + (size_t)(rbase + q)*512 + halfp*256 + Bb*64 + cL*4) = pk;
      }
    }
  }
}

// ==================== CSR build ====================
__global__ __launch_bounds__(1024) void k_scan1(const int* __restrict__ counts,
    int* __restrict__ offs, int* __restrict__ bsum)
{
  __shared__ int wsum[16];
  const int t = threadIdx.x, lane = t & 63, w = t >> 6;
  int i = blockIdx.x*1024 + t;
  int v = (i < N_NODES) ? counts[i] : 0;
  int s = v;
#pragma unroll
  for (int d = 1; d < 64; d <<= 1){ int u = __shfl_up(s, d, 64); if (lane >= d) s += u; }
  if (lane == 63) wsum[w] = s;
  __syncthreads();
  if (w == 0){
    int ws = (lane < 16) ? wsum[lane] : 0;
#pragma unroll
    for (int d = 1; d < 16; d <<= 1){ int u = __shfl_up(ws, d, 64); if (lane >= d) ws += u; }
    if (lane < 16) wsum[lane] = ws;
  }
  __syncthreads();
  int wbase = (w == 0) ? 0 : wsum[w-1];
  if (i < N_NODES) offs[i] = wbase + s - v;
  if (t == 0) bsum[blockIdx.x] = wsum[15];
}

__global__ void k_scan2(int* __restrict__ bsum, int* __restrict__ offs){
  __shared__ int wtot;
  const int t = threadIdx.x, lane = t & 63, w = t >> 6;  // 128 threads
  int v = (t < SCAN_B) ? bsum[t] : 0;
  int s = v;
#pragma unroll
  for (int d = 1; d < 64; d <<= 1){ int u = __shfl_up(s, d, 64); if (lane >= d) s += u; }
  if (t == 63) wtot = s;
  __syncthreads();
  int base = (w == 1) ? wtot : 0;
  int excl = base + s - v;
  if (t < SCAN_B) bsum[t] = excl;
  if (t == SCAN_B-1) offs[N_NODES] = excl + v;
}

__global__ __launch_bounds__(1024) void k_scan3(const int* __restrict__ bsum,
    int* __restrict__ offs, int* __restrict__ cursor)
{
  int i = blockIdx.x*1024 + threadIdx.x;
  if (i < N_NODES){
    int o = offs[i] + bsum[blockIdx.x];
    offs[i] = o; cursor[i] = o;
  }
}

__global__ void k_fill(const int* __restrict__ ei, int* __restrict__ cursor,
                       int* __restrict__ lstS, int* __restrict__ lstD, int* __restrict__ lstE){
  int e = blockIdx.x*256 + threadIdx.x;
  if (e < N_EDGES){
    int s = ei[e], d = ei[N_EDGES + e];
    int slot = atomicAdd(&cursor[d], 1);
    lstS[slot] = s; lstD[slot] = d; lstE[slot] = e;
  }
}

// ==================== mean aggregation (bf16): 16 lanes/node, uint4, 4-deep ====================
#define AGG_ACC(v) \
  a0 += __uint_as_float((v).x<<16); a1 += __uint_as_float((v).x & 0xFFFF0000u); \
  a2 += __uint_as_float((v).y<<16); a3 += __uint_as_float((v).y & 0xFFFF0000u); \
  a4 += __uint_as_float((v).z<<16); a5 += __uint_as_float((v).z & 0xFFFF0000u); \
  a6 += __uint_as_float((v).w<<16); a7 += __uint_as_float((v).w & 0xFFFF0000u);

__global__ __launch_bounds__(256) void k_agg(const u16* __restrict__ hb,
    const int* __restrict__ offs, const int* __restrict__ lst, u16* __restrict__ meanb)
{
  const int node = blockIdx.x*16 + (threadIdx.x >> 4);
  if (node >= NPAD) return;
  const int l16 = threadIdx.x & 15;
  int beg = 0, end = 0;
  if (node < N_NODES){ beg = offs[node]; end = offs[node+1]; }
  float a0=0.f,a1=0.f,a2=0.f,a3=0.f,a4=0.f,a5=0.f,a6=0.f,a7=0.f;
  int p = beg;
  for (; p + 4 <= end; p += 4){
    int s0 = lst[p], s1 = lst[p+1], s2 = lst[p+2], s3 = lst[p+3];
    uint4 v0 = *(const uint4*)(hb + (size_t)s0*128 + l16*8);
    uint4 v1 = *(const uint4*)(hb + (size_t)s1*128 + l16*8);
    uint4 v2 = *(const uint4*)(hb + (size_t)s2*128 + l16*8);
    uint4 v3 = *(const uint4*)(hb + (size_t)s3*128 + l16*8);
    AGG_ACC(v0) AGG_ACC(v1) AGG_ACC(v2) AGG_ACC(v3)
  }
  for (; p < end; ++p){
    uint4 v0 = *(const uint4*)(hb + (size_t)lst[p]*128 + l16*8);
    AGG_ACC(v0)
  }
  float inv = 1.f / fmaxf((float)(end - beg), 1.f);
  uint4 o;
  o.x = bfr(a0*inv) | (bfr(a1*inv)<<16);
  o.y = bfr(a2*inv) | (bfr(a3*inv)<<16);
  o.z = bfr(a4*inv) | (bfr(a5*inv)<<16);
  o.w = bfr(a6*inv) | (bfr(a7*inv)<<16);
  *(uint4*)(meanb + (size_t)node*128 + l16*8) = o;
}

// ==================== per-edge classifier: fp8 P gathers (4x uint4/side), pinned ====
__global__ __launch_bounds__(256) void k_edge(
    const int* __restrict__ lstS, const int* __restrict__ lstD, const int* __restrict__ lstE,
    const float* __restrict__ ea, const u8* __restrict__ P8, const u16* __restrict__ Wg_e,
    const float* __restrict__ bc1, const float* __restrict__ Wc2, const float* __restrict__ bc2,
    float* __restrict__ outp)
{
  __shared__ __align__(16) u16 Bf[16*64*8];    // 16KB: A3 as MFMA A-frags (prepacked)
  __shared__ float sb[256], sw[256];
  const int t = threadIdx.x, L = t & 63, w = t >> 6;
#pragma unroll
  for (int i = 0; i < 4; ++i){
    int c = t + i*256;
    gload16(Wg_e + c*8, Bf + c*8);
  }
  sb[t] = bc1[t];
  sw[t] = Wc2[t];
  const int cL = L & 15, part = L >> 4;
  const float bc2v = bc2[0];
  const int pos0 = blockIdx.x*64 + w*16;
  const int e = lstE[pos0 + cL];
  const int s = lstS[pos0 + cL], d = lstD[pos0 + cL];
  bf16x8 eafrag;
  {
    const float* src = ea + (size_t)e*32 + part*8;
    uint4 pk = pack8(ld4(src), ld4(src+4));
    eafrag = *(bf16x8*)&pk;
  }
  const u8* p1base = P8 + (size_t)s*512 + part*16;
  const u8* p2base = P8 + (size_t)d*512 + 256 + part*16;
  uint4 g1[4], g2[4];
#pragma unroll
  for (int B = 0; B < 4; ++B){
    g1[B] = *(const uint4*)(p1base + B*64);
    g2[B] = *(const uint4*)(p2base + B*64);
  }
  // pin all 8 gathers in flight
  __builtin_amdgcn_sched_barrier(0);
#pragma unroll
  for (int B = 0; B < 4; ++B){
    asm volatile("" :: "v"(g1[B].x), "v"(g1[B].y), "v"(g1[B].z), "v"(g1[B].w),
                       "v"(g2[B].x), "v"(g2[B].y), "v"(g2[B].z), "v"(g2[B].w));
  }
  __syncthreads();
  float osum = 0.f;
#pragma unroll
  for (int B = 0; B < 4; ++B){
    const u32 w1[4] = {g1[B].x, g1[B].y, g1[B].z, g1[B].w};
    const u32 w2[4] = {g2[B].x, g2[B].y, g2[B].z, g2[B].w};
    float p1v[4][4], p2v[4][4];   // [q][jbl]
#pragma unroll
    for (int q = 0; q < 4; ++q){
      f32x2 l1 = __builtin_amdgcn_cvt_pk_f32_fp8((int)w1[q], false);
      f32x2 h1 = __builtin_amdgcn_cvt_pk_f32_fp8((int)w1[q], true);
      f32x2 l2 = __builtin_amdgcn_cvt_pk_f32_fp8((int)w2[q], false);
      f32x2 h2 = __builtin_amdgcn_cvt_pk_f32_fp8((int)w2[q], true);
      p1v[q][0] = l1.x; p1v[q][1] = l1.y; p1v[q][2] = h1.x; p1v[q][3] = h1.y;
      p2v[q][0] = l2.x; p2v[q][1] = l2.y; p2v[q][2] = h2.x; p2v[q][3] = h2.y;
    }
#pragma unroll
    for (int jbl = 0; jbl < 4; ++jbl){
      const int jb = 4*B + jbl;
      f32x4 acc = {0.f,0.f,0.f,0.f};
      bf16x8 afr = *(const bf16x8*)(Bf + ((jb*64 + L)<<3));
      acc = __builtin_amdgcn_mfma_f32_16x16x32_bf16(afr, eafrag, acc, 0, 0, 0);
      float4 bb = *(const float4*)&sb[jb*16 + part*4];
      float4 ww = *(const float4*)&sw[jb*16 + part*4];
      float bbv[4]={bb.x,bb.y,bb.z,bb.w}, wwv[4]={ww.x,ww.y,ww.z,ww.w};
#pragma unroll
      for (int q = 0; q < 4; ++q){
        float hid = fmaxf(acc[q] + (p1v[q][jbl] + p2v[q][jbl])*0.0625f + bbv[q], 0.f);
        osum = fmaf(wwv[q], hid, osum);
      }
    }
  }
  osum += __shfl_xor(osum, 16, 64);
  osum += __shfl_xor(osum, 32, 64);
  if (L < 16) outp[e] = osum + bc2v;
}

extern "C" void kernel_launch(void* const* d_in, const int* in_sizes, int n_in,
                              void* d_out, int out_size, void* d_ws, size_t ws_size,
                              hipStream_t stream)
{
  const float* x   = (const float*)d_in[0];
  const float* h0  = (const float*)d_in[1];
  const int*   ei  = (const int*)d_in[2];
  const float* ea  = (const float*)d_in[3];
  const float* Wih = (const float*)d_in[4];
  const float* Whh = (const float*)d_in[5];
  const float* bih = (const float*)d_in[6];
  const float* bhh = (const float*)d_in[7];
  const float* Wl[3] = {(const float*)d_in[8],  (const float*)d_in[11], (const float*)d_in[14]};
  const float* bl[3] = {(const float*)d_in[9],  (const float*)d_in[12], (const float*)d_in[15]};
  const float* Wr[3] = {(const float*)d_in[10], (const float*)d_in[13], (const float*)d_in[16]};
  const float* Wc1 = (const float*)d_in[17];
  const float* bc1 = (const float*)d_in[18];
  const float* Wc2 = (const float*)d_in[19];
  const float* bc2 = (const float*)d_in[20];

  float* out  = (float*)d_out;
  float* hfin = (float*)d_out + N_EDGES;

  char* wp = (char*)d_ws;
  auto alloc = [&](size_t bytes) -> void* {
    void* p = (void*)wp; wp += (bytes + 255) & ~(size_t)255; return p;
  };
  u16* xb   = (u16*)alloc((size_t)NPAD*128*2);
  u16* h0b  = (u16*)alloc((size_t)NPAD*128*2);
  u16* hA   = (u16*)alloc((size_t)NPAD*128*2);
  u16* hB   = (u16*)alloc((size_t)NPAD*128*2);
  u16* mb   = (u16*)alloc((size_t)NPAD*128*2);
  u8*  GP8  = (u8*) alloc((size_t)NPAD*512);
  u16* Wg_g = (u16*)alloc((size_t)16384*16);
  u16* Wg_s0= (u16*)alloc((size_t)4096*16);
  u16* Wg_s1= (u16*)alloc((size_t)4096*16);
  u16* Wg_s2= (u16*)alloc((size_t)4096*16);
  u16* Wg_p = (u16*)alloc((size_t)8192*16);
  u16* Wg_e = (u16*)alloc((size_t)1024*16);
  int* counts=(int*)alloc((size_t)N_NODES*4);
  int* cursor=(int*)alloc((size_t)N_NODES*4);
  int* offs  =(int*)alloc((size_t)(N_NODES+1)*4);
  int* bsum  =(int*)alloc((size_t)SCAN_B*4);
  int* lstS  =(int*)alloc((size_t)N_EDGES*4);
  int* lstD  =(int*)alloc((size_t)N_EDGES*4);
  int* lstE  =(int*)alloc((size_t)N_EDGES*4);

  const dim3 b256(256);

  // fused prep (cast + count + packs), then scan + fill
  (void)hipMemsetAsync(counts, 0, (size_t)N_NODES*4, stream);
  k_prep<<<dim3(PREP_BLOCKS), b256, 0, stream>>>(
      x, h0, xb, h0b, ei, counts,
      Wih, Whh, Wg_g,
      Wl[0], Wr[0], Wg_s0, Wl[1], Wr[1], Wg_s1, Wl[2], Wr[2], Wg_s2,
      Wc1, Wg_p, Wg_e);
  k_scan1<<<dim3(SCAN_B), dim3(1024), 0, stream>>>(counts, offs, bsum);
  k_scan2<<<dim3(1), dim3(128), 0, stream>>>(bsum, offs);
  k_scan3<<<dim3(SCAN_B), dim3(1024), 0, stream>>>(bsum, offs, cursor);
  k_fill<<<dim3((N_EDGES+255)/256), b256, 0, stream>>>(ei, cursor, lstS, lstD, lstE);

  // GRU: 2-phase A-stationary fused GEMM + gates -> hA (bf16); h0 blended from LDS
  k_mm3<3,128><<<dim3(4,782), b256, 0, stream>>>(xb, h0b, Wg_g, nullptr, hA, bih, bhh);

  // SAGE 1,2 (2-phase A-stationary); SAGE3 fused with P GEMM (fp8 P out)
  k_agg<<<dim3(6256), b256, 0, stream>>>(hA, offs, lstS, mb);
  k_mm3<1,128><<<dim3(1,782), b256, 0, stream>>>(mb, hA, Wg_s0, bl[0], hB, nullptr, nullptr);
  k_agg<<<dim3(6256), b256, 0, stream>>>(hB, offs, lstS, mb);
  k_mm3<1,128><<<dim3(1,782), b256, 0, stream>>>(mb, hB, Wg_s1, bl[1], hA, nullptr, nullptr);
  k_agg<<<dim3(6256), b256, 0, stream>>>(hA, offs, lstS, mb);
  k_sage3p<<<dim3(782), b256, 0, stream>>>(mb, hA, Wg_s2, bl[2], Wg_p, hfin, GP8);

  // per-edge classifier in CSR order
  k_edge<<<dim3(9375), b256, 0, stream>>>(lstS, lstD, lstE, ea, GP8, Wg_e, bc1, Wc2, bc2, out);
}

// Round 20
// 383.564 us; speedup vs baseline: 1.0863x; 1.0085x over previous
//
#include <hip/hip_runtime.h>
#include <hip/hip_bf16.h>

#define N_NODES 100000
#define NPAD    100096
#define N_EDGES 600000
#define SCAN_B  98

typedef unsigned short u16;
typedef unsigned char u8;
typedef unsigned int u32;
typedef short bf16x8 __attribute__((ext_vector_type(8)));
typedef float f32x4 __attribute__((ext_vector_type(4)));
typedef float f32x2 __attribute__((ext_vector_type(2)));

__device__ __forceinline__ float4 ld4(const float* p){ return *(const float4*)p; }
__device__ __forceinline__ float sigm(float v){ return 1.0f/(1.0f + __expf(-v)); }
__device__ __forceinline__ float tanh_fast(float v){
  float e = __expf(-2.0f*fabsf(v));
  float r = (1.0f - e)/(1.0f + e);
  return copysignf(r, v);
}
// f32 -> bf16 bits, RNE
__device__ __forceinline__ u32 bfr(float f){
  u32 u = __float_as_uint(f);
  return (u + 0x7FFFu + ((u>>16)&1u)) >> 16;
}
__device__ __forceinline__ float b2f(u16 b){ return __uint_as_float(((u32)b)<<16); }
__device__ __forceinline__ uint4 pack8(float4 a, float4 b){
  uint4 r;
  r.x = bfr(a.x) | (bfr(a.y)<<16);
  r.y = bfr(a.z) | (bfr(a.w)<<16);
  r.z = bfr(b.x) | (bfr(b.y)<<16);
  r.w = bfr(b.z) | (bfr(b.w)<<16);
  return r;
}
__device__ __forceinline__ void gload16(const void* g, void* l){
  __builtin_amdgcn_global_load_lds((__attribute__((address_space(1))) void*)(g),
                                   (__attribute__((address_space(3))) void*)(l), 16, 0, 0);
}

// ==================== fused prep: cast2 + count + all weight packs ====================
#define PB_CAST   12512
#define PB_COUNT  2344
#define P0 (PB_CAST)
#define P1 (P0 + PB_COUNT)     // pack_gru (64)
#define P2 (P1 + 64)           // pack_sage l0 (16)
#define P3 (P2 + 16)           // l1
#define P4 (P3 + 16)           // l2
#define P5 (P4 + 16)           // pack_p (32)
#define P6 (P5 + 32)           // pack_e (4)
#define PREP_BLOCKS (P6 + 4)

__global__ __launch_bounds__(256) void k_prep(
    const float* __restrict__ x, const float* __restrict__ h0,
    u16* __restrict__ xb, u16* __restrict__ h0b,
    const int* __restrict__ ei, int* __restrict__ counts,
    const float* __restrict__ Wih, const float* __restrict__ Whh, u16* __restrict__ Wg,
    const float* __restrict__ Wl0, const float* __restrict__ Wr0, u16* __restrict__ Wgs0,
    const float* __restrict__ Wl1, const float* __restrict__ Wr1, u16* __restrict__ Wgs1,
    const float* __restrict__ Wl2, const float* __restrict__ Wr2, u16* __restrict__ Wgs2,
    const float* __restrict__ Wc1, u16* __restrict__ Wgp, u16* __restrict__ Wge)
{
  const int b = blockIdx.x, t = threadIdx.x;
  if (b < P0){
    int idx = b*256 + t;
    const int half = NPAD*16;
    const float* src = (idx < half) ? x : h0;
    u16* dst = (idx < half) ? xb : h0b;
    if (idx >= half) idx -= half;
    int row = idx >> 4, c8 = (idx & 15) << 3;
    float4 v0 = {0,0,0,0}, v1 = {0,0,0,0};
    if (row < N_NODES){
      v0 = ld4(src + (size_t)row*128 + c8);
      v1 = ld4(src + (size_t)row*128 + c8 + 4);
    }
    *(uint4*)(dst + (size_t)row*128 + c8) = pack8(v0, v1);
  } else if (b < P1){
    int e = (b - P0)*256 + t;
    if (e < N_EDGES) atomicAdd(&counts[ei[N_EDGES + e]], 1);
  } else if (b < P2){
    int cI = (b - P1)*256 + t;        // 16384
    int lane = cI&63, grp = (cI>>6)&7, ks = (cI>>9)&7, nb = cI>>12;
    int g = grp & 3;
    int c = (nb*2 + (grp>>2))*16 + (lane&15);
    int kg = ks*32 + ((lane>>4)<<3);
    bool xs = kg < 128;
    const float* src = nullptr;
    if (g == 0)      src = xs ? Wih + (size_t)c*128 + kg       : Whh + (size_t)c*128 + kg-128;
    else if (g == 1) src = xs ? Wih + (size_t)(128+c)*128 + kg : Whh + (size_t)(128+c)*128 + kg-128;
    else if (g == 2) src = xs ? Wih + (size_t)(256+c)*128 + kg : nullptr;
    else             src = xs ? nullptr                        : Whh + (size_t)(256+c)*128 + kg-128;
    float4 v0 = {0,0,0,0}, v1 = {0,0,0,0};
    if (src){ v0 = ld4(src); v1 = ld4(src+4); }
    ((uint4*)Wg)[cI] = pack8(v0, v1);
  } else if (b < P5){
    const float *Wl, *Wr; u16* Wo; int c;
    if (b < P3){ Wl = Wl0; Wr = Wr0; Wo = Wgs0; c = (b - P2)*256 + t; }
    else if (b < P4){ Wl = Wl1; Wr = Wr1; Wo = Wgs1; c = (b - P3)*256 + t; }
    else { Wl = Wl2; Wr = Wr2; Wo = Wgs2; c = (b - P4)*256 + t; }
    int lane = c&63, grp = (c>>6)&7, ks = c>>9;
    int col = grp*16 + (lane&15);
    int kg = ks*32 + ((lane>>4)<<3);
    const float* src = (kg < 128) ? Wl + (size_t)col*128 + kg : Wr + (size_t)col*128 + kg-128;
    ((uint4*)Wo)[c] = pack8(ld4(src), ld4(src+4));
  } else if (b < P6){
    // P pack: fp8-byte-layout permutation (half, B=pby1*2+nw, jj, cl)
    int c = (b - P5)*256 + t;         // 8192
    int lane = c&63, grp = (c>>6)&7, ks = (c>>9)&3, nb = c>>11;
    int cp = nb*128 + grp*16 + (lane&15);
    int kg = ks*32 + ((lane>>4)<<3);
    int half = cp >> 8;
    int pby1 = (cp >> 7) & 1, nw = (cp >> 6) & 1, jj = (cp >> 4) & 3, cl = cp & 15;
    int f = (pby1*2 + nw)*64 + jj*16 + cl;
    const float* src = Wc1 + (size_t)f*288 + half*128 + kg;
    ((uint4*)Wgp)[c] = pack8(ld4(src), ld4(src+4));
  } else {
    int c = (b - P6)*256 + t;         // 1024
    int lc = c & 63;
    int j = ((c>>6)<<4) + (lc & 15), k0 = (lc >> 4) << 3;
    const float* src = Wc1 + (size_t)j*288 + 256 + k0;
    ((uint4*)Wge)[c] = pack8(ld4(src), ld4(src+4));
  }
}

// ==================== 2-phase A-stationary GEMM: 32KB LDS, B streamed global->reg ====
// SWZ=1: 1D grid 3136, XCD-swizzled so the 4 column tiles of a stripe share an XCD L2.
template<int EPI, int NOUT, int SWZ>
__global__ __launch_bounds__(256) void k_mm3(
    const u16* __restrict__ A1, const u16* __restrict__ A2,
    const u16* __restrict__ Wp, const float* __restrict__ bias,
    u16* __restrict__ outB,
    const float* __restrict__ bih, const float* __restrict__ bhh)
{
  __shared__ __align__(16) u16 As[4*512*8];    // 32KB
  const int t = threadIdx.x, L = t & 63, w = t >> 6;
  const int mw = w >> 1, nw = w & 1;
  int i0, by;
  if (SWZ){
    int b = blockIdx.x;
    int xcd = b & 7, k = b >> 3;
    by = k & 3;
    int stripe = xcd + (k >> 2)*8;
    if (stripe >= 782) return;
    i0 = stripe * 128;
  } else {
    i0 = blockIdx.y * 128;
    by = blockIdx.x;
  }
  const f32x4 z4 = {0.f,0.f,0.f,0.f};
  f32x4 acc[4][4];
#pragma unroll
  for (int i=0;i<4;++i)
#pragma unroll
  for (int j=0;j<4;++j) acc[i][j] = z4;

#pragma unroll
  for (int half = 0; half < 2; ++half){
    if (half) __syncthreads();
    const u16* Asrc = half ? A2 : A1;
#pragma unroll
    for (int sh = 0; sh < 8; ++sh){
      int s = t + sh*256;
      int ks = s >> 9, rem = s & 511;
      int rg = rem >> 6, l2 = rem & 63;
      int row = i0 + rg*16 + (l2 & 15);
      int kg = ks*32 + ((l2 >> 4) << 3);
      gload16(Asrc + (size_t)row*128 + kg, As + (size_t)s*8);
    }
    __syncthreads();
#pragma unroll
    for (int ks = 0; ks < 4; ++ks){
      bf16x8 a[4], b[4];
#pragma unroll
      for (int j = 0; j < 4; ++j)
        b[j] = *(const bf16x8*)(Wp + (((size_t)(by*8 + half*4 + ks)) << 12) + ((nw*4+j)*64 + L)*8);
#pragma unroll
      for (int i = 0; i < 4; ++i)
        a[i] = *(const bf16x8*)(As + ((size_t)ks*512 + (mw*4+i)*64 + L)*8);
#pragma unroll
      for (int i = 0; i < 4; ++i)
#pragma unroll
        for (int j = 0; j < 4; ++j)
          acc[i][j] = __builtin_amdgcn_mfma_f32_16x16x32_bf16(a[i], b[j], acc[i][j], 0, 0, 0);
    }
  }
  const int r4 = (L>>4)*4, cL = L&15;
  if (EPI == 3){
    const int c = (by*2 + nw)*16 + cL;
    const float br = bih[c]     + bhh[c];
    const float bz = bih[128+c] + bhh[128+c];
    const float bi = bih[256+c];
    const float bh = bhh[256+c];
    const int ksp = c >> 5, hi = (c >> 3) & 3, jj = c & 7;
#pragma unroll
    for (int i = 0; i < 4; ++i){
      int rbase = i0 + mw*64 + i*16 + r4;
      const u16* hrow = As + ((size_t)ksp*512 + (mw*4+i)*64 + hi*16 + r4)*8 + jj;
#pragma unroll
      for (int q = 0; q < 4; ++q){
        int row = rbase + q;
        float rr = sigm(acc[i][0][q] + br);
        float zz = sigm(acc[i][1][q] + bz);
        float nn = tanh_fast(acc[i][2][q] + bi + rr*(acc[i][3][q] + bh));
        float h0v = b2f(hrow[q*8]);
        outB[(size_t)row*128 + c] = (u16)bfr((1.f - zz)*nn + zz*h0v);
      }
    }
  } else {
#pragma unroll
    for (int i = 0; i < 4; ++i){
      int rbase = i0 + mw*64 + i*16 + r4;
#pragma unroll
      for (int j = 0; j < 4; ++j){
        int col = by*128 + nw*64 + j*16 + cL;
#pragma unroll
        for (int q = 0; q < 4; ++q){
          int row = rbase + q;
          float rv = fmaxf(acc[i][j][q] + bias[col], 0.f);
          outB[(size_t)row*NOUT + col] = (u16)bfr(rv);
        }
      }
    }
  }
}

// ==================== SAGE3 + P fused; P stored fp8 (x16 scale) ====================
#define H3P 136
__global__ __launch_bounds__(256) void k_sage3p(
    const u16* __restrict__ A1, const u16* __restrict__ A2,
    const u16* __restrict__ Ws, const float* __restrict__ bias,
    const u16* __restrict__ Wp,
    float* __restrict__ hfinF, u8* __restrict__ GP8)
{
  __shared__ __align__(16) u16 As[8*512*8];    // 64KB; reused as h3 [128][H3P]
  const int t = threadIdx.x, L = t & 63, w = t >> 6;
  const int mw = w >> 1, nw = w & 1;
  const int i0 = blockIdx.x * 128;
  const int r4 = (L>>4)*4, cL = L&15;
  const f32x4 z4 = {0.f,0.f,0.f,0.f};
#pragma unroll
  for (int sh = 0; sh < 16; ++sh){
    int s = t + sh*256;
    int ks = s >> 9, rem = s & 511;
    int rg = rem >> 6, l2 = rem & 63;
    int row = i0 + rg*16 + (l2 & 15);
    int kg = ks*32 + ((l2 >> 4) << 3);
    const u16* src = (ks < 4) ? A1 + (size_t)row*128 + kg
                              : A2 + (size_t)row*128 + kg - 128;
    gload16(src, As + (size_t)s*8);
  }
  __syncthreads();
  f32x4 acc[4][4];
#pragma unroll
  for (int i=0;i<4;++i)
#pragma unroll
  for (int j=0;j<4;++j) acc[i][j] = z4;
#pragma unroll
  for (int ks = 0; ks < 8; ++ks){
    bf16x8 a[4], b[4];
#pragma unroll
    for (int j = 0; j < 4; ++j)
      b[j] = *(const bf16x8*)(Ws + (((size_t)ks) << 12) + ((nw*4+j)*64 + L)*8);
#pragma unroll
    for (int i = 0; i < 4; ++i)
      a[i] = *(const bf16x8*)(As + ((size_t)ks*512 + (mw*4+i)*64 + L)*8);
#pragma unroll
    for (int i = 0; i < 4; ++i)
#pragma unroll
      for (int j = 0; j < 4; ++j)
        acc[i][j] = __builtin_amdgcn_mfma_f32_16x16x32_bf16(a[i], b[j], acc[i][j], 0, 0, 0);
  }
  __syncthreads();
  u16* h3l = As;
#pragma unroll
  for (int i = 0; i < 4; ++i){
    int rl = mw*64 + i*16 + r4;
#pragma unroll
    for (int j = 0; j < 4; ++j){
      int col = nw*64 + j*16 + cL;
#pragma unroll
      for (int q = 0; q < 4; ++q){
        float rv = fmaxf(acc[i][j][q] + bias[col], 0.f);
        h3l[(rl + q)*H3P + col] = (u16)bfr(rv);
        int row = i0 + rl + q;
        if (row < N_NODES) hfinF[(size_t)row*128 + col] = rv;
      }
    }
  }
  __syncthreads();
  for (int pby = 0; pby < 4; ++pby){
#pragma unroll
    for (int i=0;i<4;++i)
#pragma unroll
    for (int j=0;j<4;++j) acc[i][j] = z4;
#pragma unroll
    for (int ks = 0; ks < 4; ++ks){
      bf16x8 a[4], b[4];
#pragma unroll
      for (int j = 0; j < 4; ++j)
        b[j] = *(const bf16x8*)(Wp + (((size_t)(pby*4 + ks)) << 12) + ((nw*4+j)*64 + L)*8);
      int kg = ks*32 + ((L>>4)<<3);
#pragma unroll
      for (int i = 0; i < 4; ++i){
        int rl = mw*64 + i*16 + cL;
        a[i] = *(const bf16x8*)(h3l + rl*H3P + kg);
      }
#pragma unroll
      for (int i = 0; i < 4; ++i)
#pragma unroll
        for (int j = 0; j < 4; ++j)
          acc[i][j] = __builtin_amdgcn_mfma_f32_16x16x32_bf16(a[i], b[j], acc[i][j], 0, 0, 0);
    }
    // fp8 epilogue: j-quad -> one u32; byte addr = half*256 + B*64 + cL*4 + j
    const int halfp = pby >> 1, Bb = (pby & 1)*2 + nw;
#pragma unroll
    for (int i = 0; i < 4; ++i){
      int rbase = i0 + mw*64 + i*16 + r4;
#pragma unroll
      for (int q = 0; q < 4; ++q){
        u32 pk = (u32)__builtin_amdgcn_cvt_pk_fp8_f32(acc[i][0][q]*16.f, acc[i][1][q]*16.f, 0, false);
        pk = (u32)__builtin_amdgcn_cvt_pk_fp8_f32(acc[i][2][q]*16.f, acc[i][3][q]*16.f, (int)pk, true);
        *(u32*)(GP8 + (size_t)(rbase + q)*512 + halfp*256 + Bb*64 + cL*4) = pk;
      }
    }
  }
}

// ==================== CSR build ====================
__global__ __launch_bounds__(1024) void k_scan1(const int* __restrict__ counts,
    int* __restrict__ offs, int* __restrict__ bsum)
{
  __shared__ int wsum[16];
  const int t = threadIdx.x, lane = t & 63, w = t >> 6;
  int i = blockIdx.x*1024 + t;
  int v = (i < N_NODES) ? counts[i] : 0;
  int s = v;
#pragma unroll
  for (int d = 1; d < 64; d <<= 1){ int u = __shfl_up(s, d, 64); if (lane >= d) s += u; }
  if (lane == 63) wsum[w] = s;
  __syncthreads();
  if (w == 0){
    int ws = (lane < 16) ? wsum[lane] : 0;
#pragma unroll
    for (int d = 1; d < 16; d <<= 1){ int u = __shfl_up(ws, d, 64); if (lane >= d) ws += u; }
    if (lane < 16) wsum[lane] = ws;
  }
  __syncthreads();
  int wbase = (w == 0) ? 0 : wsum[w-1];
  if (i < N_NODES) offs[i] = wbase + s - v;
  if (t == 0) bsum[blockIdx.x] = wsum[15];
}

__global__ void k_scan2(int* __restrict__ bsum, int* __restrict__ offs){
  __shared__ int wtot;
  const int t = threadIdx.x, lane = t & 63, w = t >> 6;  // 128 threads
  int v = (t < SCAN_B) ? bsum[t] : 0;
  int s = v;
#pragma unroll
  for (int d = 1; d < 64; d <<= 1){ int u = __shfl_up(s, d, 64); if (lane >= d) s += u; }
  if (t == 63) wtot = s;
  __syncthreads();
  int base = (w == 1) ? wtot : 0;
  int excl = base + s - v;
  if (t < SCAN_B) bsum[t] = excl;
  if (t == SCAN_B-1) offs[N_NODES] = excl + v;
}

__global__ __launch_bounds__(1024) void k_scan3(const int* __restrict__ bsum,
    int* __restrict__ offs, int* __restrict__ cursor)
{
  int i = blockIdx.x*1024 + threadIdx.x;
  if (i < N_NODES){
    int o = offs[i] + bsum[blockIdx.x];
    offs[i] = o; cursor[i] = o;
  }
}

__global__ void k_fill(const int* __restrict__ ei, int* __restrict__ cursor,
                       int* __restrict__ lstS, int* __restrict__ lstD, int* __restrict__ lstE){
  int e = blockIdx.x*256 + threadIdx.x;
  if (e < N_EDGES){
    int s = ei[e], d = ei[N_EDGES + e];
    int slot = atomicAdd(&cursor[d], 1);
    lstS[slot] = s; lstD[slot] = d; lstE[slot] = e;
  }
}

// ==================== mean aggregation (bf16): 16 lanes/node, uint4, 4-deep ====================
#define AGG_ACC(v) \
  a0 += __uint_as_float((v).x<<16); a1 += __uint_as_float((v).x & 0xFFFF0000u); \
  a2 += __uint_as_float((v).y<<16); a3 += __uint_as_float((v).y & 0xFFFF0000u); \
  a4 += __uint_as_float((v).z<<16); a5 += __uint_as_float((v).z & 0xFFFF0000u); \
  a6 += __uint_as_float((v).w<<16); a7 += __uint_as_float((v).w & 0xFFFF0000u);

__global__ __launch_bounds__(256) void k_agg(const u16* __restrict__ hb,
    const int* __restrict__ offs, const int* __restrict__ lst, u16* __restrict__ meanb)
{
  const int node = blockIdx.x*16 + (threadIdx.x >> 4);
  if (node >= NPAD) return;
  const int l16 = threadIdx.x & 15;
  int beg = 0, end = 0;
  if (node < N_NODES){ beg = offs[node]; end = offs[node+1]; }
  float a0=0.f,a1=0.f,a2=0.f,a3=0.f,a4=0.f,a5=0.f,a6=0.f,a7=0.f;
  int p = beg;
  for (; p + 4 <= end; p += 4){
    int s0 = lst[p], s1 = lst[p+1], s2 = lst[p+2], s3 = lst[p+3];
    uint4 v0 = *(const uint4*)(hb + (size_t)s0*128 + l16*8);
    uint4 v1 = *(const uint4*)(hb + (size_t)s1*128 + l16*8);
    uint4 v2 = *(const uint4*)(hb + (size_t)s2*128 + l16*8);
    uint4 v3 = *(const uint4*)(hb + (size_t)s3*128 + l16*8);
    AGG_ACC(v0) AGG_ACC(v1) AGG_ACC(v2) AGG_ACC(v3)
  }
  for (; p < end; ++p){
    uint4 v0 = *(const uint4*)(hb + (size_t)lst[p]*128 + l16*8);
    AGG_ACC(v0)
  }
  float inv = 1.f / fmaxf((float)(end - beg), 1.f);
  uint4 o;
  o.x = bfr(a0*inv) | (bfr(a1*inv)<<16);
  o.y = bfr(a2*inv) | (bfr(a3*inv)<<16);
  o.z = bfr(a4*inv) | (bfr(a5*inv)<<16);
  o.w = bfr(a6*inv) | (bfr(a7*inv)<<16);
  *(uint4*)(meanb + (size_t)node*128 + l16*8) = o;
}

// ==================== per-edge classifier: fp8 P gathers (4x uint4/side), pinned ====
__global__ __launch_bounds__(256) void k_edge(
    const int* __restrict__ lstS, const int* __restrict__ lstD, const int* __restrict__ lstE,
    const float* __restrict__ ea, const u8* __restrict__ P8, const u16* __restrict__ Wg_e,
    const float* __restrict__ bc1, const float* __restrict__ Wc2, const float* __restrict__ bc2,
    float* __restrict__ outp)
{
  __shared__ __align__(16) u16 Bf[16*64*8];    // 16KB: A3 as MFMA A-frags (prepacked)
  __shared__ float sb[256], sw[256];
  const int t = threadIdx.x, L = t & 63, w = t >> 6;
#pragma unroll
  for (int i = 0; i < 4; ++i){
    int c = t + i*256;
    gload16(Wg_e + c*8, Bf + c*8);
  }
  sb[t] = bc1[t];
  sw[t] = Wc2[t];
  const int cL = L & 15, part = L >> 4;
  const float bc2v = bc2[0];
  const int pos0 = blockIdx.x*64 + w*16;
  const int e = lstE[pos0 + cL];
  const int s = lstS[pos0 + cL], d = lstD[pos0 + cL];
  bf16x8 eafrag;
  {
    const float* src = ea + (size_t)e*32 + part*8;
    uint4 pk = pack8(ld4(src), ld4(src+4));
    eafrag = *(bf16x8*)&pk;
  }
  const u8* p1base = P8 + (size_t)s*512 + part*16;
  const u8* p2base = P8 + (size_t)d*512 + 256 + part*16;
  uint4 g1[4], g2[4];
#pragma unroll
  for (int B = 0; B < 4; ++B){
    g1[B] = *(const uint4*)(p1base + B*64);
    g2[B] = *(const uint4*)(p2base + B*64);
  }
  // pin all 8 gathers in flight
  __builtin_amdgcn_sched_barrier(0);
#pragma unroll
  for (int B = 0; B < 4; ++B){
    asm volatile("" :: "v"(g1[B].x), "v"(g1[B].y), "v"(g1[B].z), "v"(g1[B].w),
                       "v"(g2[B].x), "v"(g2[B].y), "v"(g2[B].z), "v"(g2[B].w));
  }
  __syncthreads();
  float osum = 0.f;
#pragma unroll
  for (int B = 0; B < 4; ++B){
    const u32 w1[4] = {g1[B].x, g1[B].y, g1[B].z, g1[B].w};
    const u32 w2[4] = {g2[B].x, g2[B].y, g2[B].z, g2[B].w};
    float p1v[4][4], p2v[4][4];   // [q][jbl]
#pragma unroll
    for (int q = 0; q < 4; ++q){
      f32x2 l1 = __builtin_amdgcn_cvt_pk_f32_fp8((int)w1[q], false);
      f32x2 h1 = __builtin_amdgcn_cvt_pk_f32_fp8((int)w1[q], true);
      f32x2 l2 = __builtin_amdgcn_cvt_pk_f32_fp8((int)w2[q], false);
      f32x2 h2 = __builtin_amdgcn_cvt_pk_f32_fp8((int)w2[q], true);
      p1v[q][0] = l1.x; p1v[q][1] = l1.y; p1v[q][2] = h1.x; p1v[q][3] = h1.y;
      p2v[q][0] = l2.x; p2v[q][1] = l2.y; p2v[q][2] = h2.x; p2v[q][3] = h2.y;
    }
#pragma unroll
    for (int jbl = 0; jbl < 4; ++jbl){
      const int jb = 4*B + jbl;
      f32x4 acc = {0.f,0.f,0.f,0.f};
      bf16x8 afr = *(const bf16x8*)(Bf + ((jb*64 + L)<<3));
      acc = __builtin_amdgcn_mfma_f32_16x16x32_bf16(afr, eafrag, acc, 0, 0, 0);
      float4 bb = *(const float4*)&sb[jb*16 + part*4];
      float4 ww = *(const float4*)&sw[jb*16 + part*4];
      float bbv[4]={bb.x,bb.y,bb.z,bb.w}, wwv[4]={ww.x,ww.y,ww.z,ww.w};
#pragma unroll
      for (int q = 0; q < 4; ++q){
        float hid = fmaxf(acc[q] + (p1v[q][jbl] + p2v[q][jbl])*0.0625f + bbv[q], 0.f);
        osum = fmaf(wwv[q], hid, osum);
      }
    }
  }
  osum += __shfl_xor(osum, 16, 64);
  osum += __shfl_xor(osum, 32, 64);
  if (L < 16) outp[e] = osum + bc2v;
}

extern "C" void kernel_launch(void* const* d_in, const int* in_sizes, int n_in,
                              void* d_out, int out_size, void* d_ws, size_t ws_size,
                              hipStream_t stream)
{
  const float* x   = (const float*)d_in[0];
  const float* h0  = (const float*)d_in[1];
  const int*   ei  = (const int*)d_in[2];
  const float* ea  = (const float*)d_in[3];
  const float* Wih = (const float*)d_in[4];
  const float* Whh = (const float*)d_in[5];
  const float* bih = (const float*)d_in[6];
  const float* bhh = (const float*)d_in[7];
  const float* Wl[3] = {(const float*)d_in[8],  (const float*)d_in[11], (const float*)d_in[14]};
  const float* bl[3] = {(const float*)d_in[9],  (const float*)d_in[12], (const float*)d_in[15]};
  const float* Wr[3] = {(const float*)d_in[10], (const float*)d_in[13], (const float*)d_in[16]};
  const float* Wc1 = (const float*)d_in[17];
  const float* bc1 = (const float*)d_in[18];
  const float* Wc2 = (const float*)d_in[19];
  const float* bc2 = (const float*)d_in[20];

  float* out  = (float*)d_out;
  float* hfin = (float*)d_out + N_EDGES;

  char* wp = (char*)d_ws;
  auto alloc = [&](size_t bytes) -> void* {
    void* p = (void*)wp; wp += (bytes + 255) & ~(size_t)255; return p;
  };
  u16* xb   = (u16*)alloc((size_t)NPAD*128*2);
  u16* h0b  = (u16*)alloc((size_t)NPAD*128*2);
  u16* hA   = (u16*)alloc((size_t)NPAD*128*2);
  u16* hB   = (u16*)alloc((size_t)NPAD*128*2);
  u16* mb   = (u16*)alloc((size_t)NPAD*128*2);
  u8*  GP8  = (u8*) alloc((size_t)NPAD*512);
  u16* Wg_g = (u16*)alloc((size_t)16384*16);
  u16* Wg_s0= (u16*)alloc((size_t)4096*16);
  u16* Wg_s1= (u16*)alloc((size_t)4096*16);
  u16* Wg_s2= (u16*)alloc((size_t)4096*16);
  u16* Wg_p = (u16*)alloc((size_t)8192*16);
  u16* Wg_e = (u16*)alloc((size_t)1024*16);
  int* counts=(int*)alloc((size_t)N_NODES*4);
  int* cursor=(int*)alloc((size_t)N_NODES*4);
  int* offs  =(int*)alloc((size_t)(N_NODES+1)*4);
  int* bsum  =(int*)alloc((size_t)SCAN_B*4);
  int* lstS  =(int*)alloc((size_t)N_EDGES*4);
  int* lstD  =(int*)alloc((size_t)N_EDGES*4);
  int* lstE  =(int*)alloc((size_t)N_EDGES*4);

  const dim3 b256(256);

  // fused prep (cast + count + packs), then scan + fill
  (void)hipMemsetAsync(counts, 0, (size_t)N_NODES*4, stream);
  k_prep<<<dim3(PREP_BLOCKS), b256, 0, stream>>>(
      x, h0, xb, h0b, ei, counts,
      Wih, Whh, Wg_g,
      Wl[0], Wr[0], Wg_s0, Wl[1], Wr[1], Wg_s1, Wl[2], Wr[2], Wg_s2,
      Wc1, Wg_p, Wg_e);
  k_scan1<<<dim3(SCAN_B), dim3(1024), 0, stream>>>(counts, offs, bsum);
  k_scan2<<<dim3(1), dim3(128), 0, stream>>>(bsum, offs);
  k_scan3<<<dim3(SCAN_B), dim3(1024), 0, stream>>>(bsum, offs, cursor);
  k_fill<<<dim3((N_EDGES+255)/256), b256, 0, stream>>>(ei, cursor, lstS, lstD, lstE);

  // GRU: 2-phase A-stationary fused GEMM + gates -> hA (bf16); XCD-swizzled grid
  k_mm3<3,128,1><<<dim3(3136), b256, 0, stream>>>(xb, h0b, Wg_g, nullptr, hA, bih, bhh);

  // SAGE 1,2 (2-phase A-stationary); SAGE3 fused with P GEMM (fp8 P out)
  k_agg<<<dim3(6256), b256, 0, stream>>>(hA, offs, lstS, mb);
  k_mm3<1,128,0><<<dim3(1,782), b256, 0, stream>>>(mb, hA, Wg_s0, bl[0], hB, nullptr, nullptr);
  k_agg<<<dim3(6256), b256, 0, stream>>>(hB, offs, lstS, mb);
  k_mm3<1,128,0><<<dim3(1,782), b256, 0, stream>>>(mb, hB, Wg_s1, bl[1], hA, nullptr, nullptr);
  k_agg<<<dim3(6256), b256, 0, stream>>>(hA, offs, lstS, mb);
  k_sage3p<<<dim3(782), b256, 0, stream>>>(mb, hA, Wg_s2, bl[2], Wg_p, hfin, GP8);

  // per-edge classifier in CSR order
  k_edge<<<dim3(9375), b256, 0, stream>>>(lstS, lstD, lstE, ea, GP8, Wg_e, bc1, Wc2, bc2, out);
}